// Round 1
// baseline (1083.963 us; speedup 1.0000x reference)
//
#include <hip/hip_runtime.h>
#include <stdint.h>

#define NUM_CLASSES 80
#define TOPK 1000
#define NBINS 4096          // top 12 bits of flipped float key
#define CAP 4096            // candidate capacity
#define CONF_THRESH 0.05f
#define NMS_THRESH 0.6f
#define CTR_CLAMP 32.0f
#define SCALE_CLAMP 4.135166556742356f  // log(1000/16)
#define CLASS_OFFSET 100000.0f
#define ANCH_STRIDE 32.0f

__device__ __forceinline__ unsigned int flip_key(unsigned int u) {
    // order-preserving map float bits -> unsigned (larger float => larger key)
    return (u & 0x80000000u) ? ~u : (u | 0x80000000u);
}
__device__ __forceinline__ float unflip_key(unsigned int k) {
    unsigned int u = (k & 0x80000000u) ? (k ^ 0x80000000u) : ~k;
    return __uint_as_float(u);
}

__global__ void hist_k(const float* __restrict__ cls, int M, unsigned int* __restrict__ hist) {
    int i = blockIdx.x * blockDim.x + threadIdx.x;
    int stride = gridDim.x * blockDim.x;
    for (; i < M; i += stride) {
        unsigned int key = flip_key(__float_as_uint(cls[i]));
        atomicAdd(&hist[key >> 20], 1u);
    }
}

__global__ __launch_bounds__(1024) void scan_k(const unsigned int* __restrict__ hist,
                                               unsigned int* __restrict__ binB) {
    __shared__ unsigned int h[NBINS];
    __shared__ unsigned int suf[1024];
    int t = threadIdx.x;
    for (int i = t; i < NBINS; i += 1024) h[i] = hist[i];
    __syncthreads();
    unsigned int s = h[4 * t] + h[4 * t + 1] + h[4 * t + 2] + h[4 * t + 3];
    suf[t] = s;
    __syncthreads();
    // Hillis-Steele suffix scan over 1024 chunk sums
    for (int off = 1; off < 1024; off <<= 1) {
        unsigned int v = (t + off < 1024) ? suf[t + off] : 0u;
        __syncthreads();
        suf[t] += v;
        __syncthreads();
    }
    unsigned int mine = suf[t];
    unsigned int nxt = (t < 1023) ? suf[t + 1] : 0u;
    if (mine >= (unsigned)TOPK && nxt < (unsigned)TOPK) {
        // boundary bin is in my 4-bin chunk; scan from top
        unsigned int c = nxt;
        int b = 4 * t;
        for (int bin = 4 * t + 3; bin >= 4 * t; --bin) {
            c += h[bin];
            if (c >= (unsigned)TOPK) { b = bin; break; }
        }
        *binB = (unsigned int)b;
    }
}

__global__ void compact_k(const float* __restrict__ cls, int M,
                          const unsigned int* __restrict__ binB,
                          unsigned int* __restrict__ counter,
                          unsigned int* __restrict__ cand) {
    unsigned int b = *binB;
    int i = blockIdx.x * blockDim.x + threadIdx.x;
    int stride = gridDim.x * blockDim.x;
    for (; i < M; i += stride) {
        unsigned int key = flip_key(__float_as_uint(cls[i]));
        if ((key >> 20) >= b) {
            unsigned int p = atomicAdd(counter, 1u);
            if (p < (unsigned)CAP) cand[p] = (unsigned int)i;
        }
    }
}

__global__ __launch_bounds__(1024) void final_k(
    const float* __restrict__ cls, const float* __restrict__ regp,
    const float* __restrict__ anchor_size,
    const int* __restrict__ fmp_h_p, const int* __restrict__ fmp_w_p,
    const int* __restrict__ img_h_p, const int* __restrict__ img_w_p,
    int ka, const unsigned int* __restrict__ counter,
    const unsigned int* __restrict__ cand, float* __restrict__ out)
{
    __shared__ uint64_t skey[CAP];                       // 32 KB
    __shared__ float sx1[TOPK], sy1[TOPK], sx2[TOPK], sy2[TOPK], sarea[TOPK]; // 20 KB
    __shared__ int skeep[TOPK];                          // 4 KB
    int tid = threadIdx.x;
    unsigned int cnt = *counter;
    int N = (cnt < (unsigned)CAP) ? (int)cnt : CAP;

    // build composite keys: value desc, index asc on ties (matches lax.top_k)
    for (int s = tid; s < CAP; s += 1024) {
        uint64_t k = 0;
        if (s < N) {
            unsigned int idx = cand[s];
            unsigned int key = flip_key(__float_as_uint(cls[idx]));
            k = ((uint64_t)key << 32) | (uint64_t)(0xFFFFFFFFu - idx);
        }
        skey[s] = k;
    }
    __syncthreads();

    // bitonic sort, descending
    for (int k = 2; k <= CAP; k <<= 1) {
        for (int j = k >> 1; j > 0; j >>= 1) {
            for (int i = tid; i < CAP; i += 1024) {
                int l = i ^ j;
                if (l > i) {
                    uint64_t a = skey[i], b = skey[l];
                    bool desc = ((i & k) == 0);
                    if (desc ? (a < b) : (a > b)) { skey[i] = b; skey[l] = a; }
                }
            }
            __syncthreads();
        }
    }

    int fmp_w = *fmp_w_p;
    (void)fmp_h_p;
    float prob = 0.0f, lblf = 0.0f;
    float bx0 = 0.f, bx1v = 0.f, bx2v = 0.f, bx3v = 0.f;
    if (tid < TOPK) {
        if (tid < N) {
            uint64_t k = skey[tid];
            unsigned int idx = 0xFFFFFFFFu - (unsigned int)(k & 0xFFFFFFFFull);
            unsigned int keyhi = (unsigned int)(k >> 32);
            float logit = unflip_key(keyhi);
            prob = 1.0f / (1.0f + expf(-logit));
            int label = (int)(idx % NUM_CLASSES);
            int aidx = (int)(idx / NUM_CLASSES);
            int g = aidx / ka, kk = aidx % ka;
            int xg = g % fmp_w, yg = g / fmp_w;
            float ax = (xg + 0.5f) * ANCH_STRIDE, ay = (yg + 0.5f) * ANCH_STRIDE;
            float aw = anchor_size[kk * 2 + 0], ah = anchor_size[kk * 2 + 1];
            float r0 = regp[aidx * 4 + 0], r1 = regp[aidx * 4 + 1];
            float r2 = regp[aidx * 4 + 2], r3 = regp[aidx * 4 + 3];
            float ox = fminf(fmaxf(r0 * aw, -CTR_CLAMP), CTR_CLAMP);
            float oy = fminf(fmaxf(r1 * ah, -CTR_CLAMP), CTR_CLAMP);
            float cx = ax + ox, cy = ay + oy;
            float w = aw * expf(fminf(r2, SCALE_CLAMP));
            float h = ah * expf(fminf(r3, SCALE_CLAMP));
            bx0 = cx - 0.5f * w; bx1v = cy - 0.5f * h;
            bx2v = cx + 0.5f * w; bx3v = cy + 0.5f * h;
            lblf = (float)label;
            float off = lblf * CLASS_OFFSET;
            float x1o = bx0 + off, y1o = bx1v + off, x2o = bx2v + off, y2o = bx3v + off;
            sx1[tid] = x1o; sy1[tid] = y1o; sx2[tid] = x2o; sy2[tid] = y2o;
            sarea[tid] = (x2o - x1o) * (y2o - y1o);   // areas from OFFSET coords, like ref
            skeep[tid] = (prob > CONF_THRESH) ? 1 : 0;
        } else {
            sx1[tid] = 0.f; sy1[tid] = 0.f; sx2[tid] = 0.f; sy2[tid] = 0.f;
            sarea[tid] = 0.f; skeep[tid] = 0;
        }
    }
    __syncthreads();

    // cache own box in registers
    float mx1 = 0.f, my1 = 0.f, mx2 = 0.f, my2 = 0.f, mar = 0.f;
    if (tid < TOPK) { mx1 = sx1[tid]; my1 = sy1[tid]; mx2 = sx2[tid]; my2 = sy2[tid]; mar = sarea[tid]; }

    // greedy sequential NMS, one barrier per candidate
    for (int i = 0; i < TOPK; ++i) {
        if (skeep[i]) {
            float bx1c = sx1[i], by1c = sy1[i], bx2c = sx2[i], by2c = sy2[i], barc = sarea[i];
            if (tid > i && tid < TOPK && skeep[tid]) {
                float xx1 = fmaxf(bx1c, mx1);
                float yy1 = fmaxf(by1c, my1);
                float xx2 = fminf(bx2c, mx2);
                float yy2 = fminf(by2c, my2);
                float w = fmaxf(1e-28f, xx2 - xx1);
                float h = fmaxf(1e-28f, yy2 - yy1);
                float inter = w * h;
                float iou = inter / (barc + mar - inter + 1e-14f);
                if (iou > NMS_THRESH) skeep[tid] = 0;
            }
        }
        __syncthreads();
    }

    if (tid < TOPK) {
        float keepf = (float)skeep[tid];
        float img_w = (float)(*img_w_p), img_h = (float)(*img_h_p);
        float v0 = fminf(fmaxf(bx0 / img_w, 0.0f), 1.0f);
        float v1 = fminf(fmaxf(bx1v / img_h, 0.0f), 1.0f);
        float v2 = fminf(fmaxf(bx2v / img_w, 0.0f), 1.0f);
        float v3 = fminf(fmaxf(bx3v / img_h, 0.0f), 1.0f);
        out[tid * 4 + 0] = v0 * keepf;
        out[tid * 4 + 1] = v1 * keepf;
        out[tid * 4 + 2] = v2 * keepf;
        out[tid * 4 + 3] = v3 * keepf;
        out[4 * TOPK + tid] = prob * keepf;
        out[5 * TOPK + tid] = lblf;
        out[6 * TOPK + tid] = keepf;
    }
}

extern "C" void kernel_launch(void* const* d_in, const int* in_sizes, int n_in,
                              void* d_out, int out_size, void* d_ws, size_t ws_size,
                              hipStream_t stream) {
    const float* cls = (const float*)d_in[0];
    const float* regp = (const float*)d_in[1];
    const float* anchor_size = (const float*)d_in[2];
    const int* fmp_h = (const int*)d_in[3];
    const int* fmp_w = (const int*)d_in[4];
    const int* img_h = (const int*)d_in[5];
    const int* img_w = (const int*)d_in[6];
    int M = in_sizes[0];          // m * NUM_CLASSES
    int ka = in_sizes[2] / 2;

    unsigned int* hist = (unsigned int*)d_ws;       // NBINS
    unsigned int* counter = hist + NBINS;           // 1
    unsigned int* binB = counter + 1;               // 1
    unsigned int* cand = binB + 1;                  // CAP

    hipMemsetAsync(d_ws, 0, (size_t)(NBINS + 2) * sizeof(unsigned int), stream);

    int threads = 256;
    int blocks = (M + threads - 1) / threads;
    if (blocks > 2048) blocks = 2048;
    hist_k<<<blocks, threads, 0, stream>>>(cls, M, hist);
    scan_k<<<1, 1024, 0, stream>>>(hist, binB);
    compact_k<<<blocks, threads, 0, stream>>>(cls, M, binB, counter, cand);
    final_k<<<1, 1024, 0, stream>>>(cls, regp, anchor_size, fmp_h, fmp_w, img_h, img_w,
                                    ka, counter, cand, (float*)d_out);
}

// Round 2
// 194.714 us; speedup vs baseline: 5.5670x; 5.5670x over previous
//
#include <hip/hip_runtime.h>
#include <stdint.h>

#define NUM_CLASSES 80
#define TOPK 1000
#define NBINS 4096          // top 12 bits of flipped float key
#define CAP 4096            // candidate capacity
#define MAXPC 128           // max boxes per class supported in NMS lists
#define CONF_THRESH 0.05f
#define NMS_THRESH 0.6f
#define CTR_CLAMP 32.0f
#define SCALE_CLAMP 4.135166556742356f  // log(1000/16)
#define ANCH_STRIDE 32.0f

__device__ __forceinline__ unsigned int flip_key(unsigned int u) {
    return (u & 0x80000000u) ? ~u : (u | 0x80000000u);
}
__device__ __forceinline__ float unflip_key(unsigned int k) {
    unsigned int u = (k & 0x80000000u) ? (k ^ 0x80000000u) : ~k;
    return __uint_as_float(u);
}

// ---- histogram with LDS privatization (kills global atomic contention) ----
__global__ __launch_bounds__(256) void hist_k(const float* __restrict__ cls, int M,
                                              unsigned int* __restrict__ hist) {
    __shared__ unsigned int h[NBINS];
    for (int i = threadIdx.x; i < NBINS; i += 256) h[i] = 0u;
    __syncthreads();
    int i = blockIdx.x * blockDim.x + threadIdx.x;
    int stride = gridDim.x * blockDim.x;
    for (; i < M; i += stride) {
        unsigned int key = flip_key(__float_as_uint(cls[i]));
        atomicAdd(&h[key >> 20], 1u);
    }
    __syncthreads();
    for (int i = threadIdx.x; i < NBINS; i += 256) {
        unsigned int v = h[i];
        if (v) atomicAdd(&hist[i], v);
    }
}

__global__ __launch_bounds__(1024) void scan_k(const unsigned int* __restrict__ hist,
                                               unsigned int* __restrict__ binB) {
    __shared__ unsigned int h[NBINS];
    __shared__ unsigned int suf[1024];
    int t = threadIdx.x;
    for (int i = t; i < NBINS; i += 1024) h[i] = hist[i];
    __syncthreads();
    unsigned int s = h[4 * t] + h[4 * t + 1] + h[4 * t + 2] + h[4 * t + 3];
    suf[t] = s;
    __syncthreads();
    for (int off = 1; off < 1024; off <<= 1) {
        unsigned int v = (t + off < 1024) ? suf[t + off] : 0u;
        __syncthreads();
        suf[t] += v;
        __syncthreads();
    }
    unsigned int mine = suf[t];
    unsigned int nxt = (t < 1023) ? suf[t + 1] : 0u;
    if (mine >= (unsigned)TOPK && nxt < (unsigned)TOPK) {
        unsigned int c = nxt;
        int b = 4 * t;
        for (int bin = 4 * t + 3; bin >= 4 * t; --bin) {
            c += h[bin];
            if (c >= (unsigned)TOPK) { b = bin; break; }
        }
        *binB = (unsigned int)b;
    }
}

// ---- compaction with wave-aggregated atomic append ----
__global__ __launch_bounds__(256) void compact_k(const float* __restrict__ cls, int M,
                          const unsigned int* __restrict__ binB,
                          unsigned int* __restrict__ counter,
                          unsigned int* __restrict__ cand) {
    unsigned int b = *binB;
    int lane = threadIdx.x & 63;
    int i = blockIdx.x * blockDim.x + threadIdx.x;
    int stride = gridDim.x * blockDim.x;
    for (; i < M; i += stride) {
        unsigned int key = flip_key(__float_as_uint(cls[i]));
        bool pred = ((key >> 20) >= b);
        unsigned long long m = __ballot(pred);
        if (m) {
            int leader = __ffsll(m) - 1;
            unsigned int base = 0;
            if (lane == leader) base = atomicAdd(counter, (unsigned int)__popcll(m));
            base = (unsigned int)__shfl((int)base, leader);
            if (pred) {
                unsigned int off = (unsigned int)__popcll(m & ((1ull << lane) - 1ull));
                unsigned int p = base + off;
                if (p < (unsigned)CAP) cand[p] = (unsigned int)i;
            }
        }
    }
}

// ---- final: sort + decode + per-class wave NMS + output ----
__global__ __launch_bounds__(1024) void final_k(
    const float* __restrict__ cls, const float* __restrict__ regp,
    const float* __restrict__ anchor_size,
    const int* __restrict__ fmp_h_p, const int* __restrict__ fmp_w_p,
    const int* __restrict__ img_h_p, const int* __restrict__ img_w_p,
    int ka, const unsigned int* __restrict__ counter,
    const unsigned int* __restrict__ cand, float* __restrict__ out)
{
    __shared__ uint64_t poolRaw[5856];                 // 46848 B, aliased regions
    uint64_t* skey = poolRaw;                          // [CAP] during sort phase
    uint8_t* pb = (uint8_t*)poolRaw;
    float* bx1 = (float*)(pb + 0);                     // [TOPK]
    float* by1 = (float*)(pb + 4000);
    float* bx2 = (float*)(pb + 8000);
    float* by2 = (float*)(pb + 12000);
    float* bar = (float*)(pb + 16000);
    unsigned short* slab = (unsigned short*)(pb + 20000);  // [TOPK]
    int* skeep = (int*)(pb + 22000);                   // [TOPK]
    unsigned short* clist = (unsigned short*)(pb + 26000); // [80*MAXPC] = 20480 B
    int* scount = (int*)(pb + 46480);                  // [80]

    int tid = threadIdx.x;
    unsigned int cnt = *counter;
    int N = (cnt < (unsigned)CAP) ? (int)cnt : CAP;

    // build composite keys: value desc, index asc on ties (matches lax.top_k)
    for (int s = tid; s < CAP; s += 1024) {
        uint64_t k = 0;
        if (s < N) {
            unsigned int idx = cand[s];
            unsigned int key = flip_key(__float_as_uint(cls[idx]));
            k = ((uint64_t)key << 32) | (uint64_t)(0xFFFFFFFFu - idx);
        }
        skey[s] = k;
    }
    __syncthreads();

    // bitonic sort, descending
    for (int k = 2; k <= CAP; k <<= 1) {
        for (int j = k >> 1; j > 0; j >>= 1) {
            for (int i = tid; i < CAP; i += 1024) {
                int l = i ^ j;
                if (l > i) {
                    uint64_t a = skey[i], b = skey[l];
                    bool desc = ((i & k) == 0);
                    if (desc ? (a < b) : (a > b)) { skey[i] = b; skey[l] = a; }
                }
            }
            __syncthreads();
        }
    }

    // pull my key into registers before aliasing the key region
    uint64_t mykey = (tid < TOPK) ? skey[tid] : 0;
    __syncthreads();

    int fmp_w = *fmp_w_p;
    (void)fmp_h_p;
    float prob = 0.0f, lblf = 0.0f;
    float b0 = 0.f, b1 = 0.f, b2 = 0.f, b3 = 0.f;
    if (tid < TOPK) {
        if (tid < N) {
            unsigned int idx = 0xFFFFFFFFu - (unsigned int)(mykey & 0xFFFFFFFFull);
            float logit = unflip_key((unsigned int)(mykey >> 32));
            prob = 1.0f / (1.0f + expf(-logit));
            int label = (int)(idx % NUM_CLASSES);
            int aidx = (int)(idx / NUM_CLASSES);
            int g = aidx / ka, kk = aidx % ka;
            int xg = g % fmp_w, yg = g / fmp_w;
            float ax = (xg + 0.5f) * ANCH_STRIDE, ay = (yg + 0.5f) * ANCH_STRIDE;
            float aw = anchor_size[kk * 2 + 0], ah = anchor_size[kk * 2 + 1];
            float r0 = regp[aidx * 4 + 0], r1 = regp[aidx * 4 + 1];
            float r2 = regp[aidx * 4 + 2], r3 = regp[aidx * 4 + 3];
            float ox = fminf(fmaxf(r0 * aw, -CTR_CLAMP), CTR_CLAMP);
            float oy = fminf(fmaxf(r1 * ah, -CTR_CLAMP), CTR_CLAMP);
            float cx = ax + ox, cy = ay + oy;
            float w = aw * expf(fminf(r2, SCALE_CLAMP));
            float h = ah * expf(fminf(r3, SCALE_CLAMP));
            b0 = cx - 0.5f * w; b1 = cy - 0.5f * h;
            b2 = cx + 0.5f * w; b3 = cy + 0.5f * h;
            lblf = (float)label;
            bx1[tid] = b0; by1[tid] = b1; bx2[tid] = b2; by2[tid] = b3;
            bar[tid] = (b2 - b0) * (b3 - b1);   // class offset cancels: same values as ref
            slab[tid] = (unsigned short)label;
            skeep[tid] = (prob > CONF_THRESH) ? 1 : 0;
        } else {
            bx1[tid] = 0.f; by1[tid] = 0.f; bx2[tid] = 0.f; by2[tid] = 0.f;
            bar[tid] = 0.f; slab[tid] = 0; skeep[tid] = 0;
        }
    }
    __syncthreads();

    // stable per-class lists (rank-ascending), one thread per class
    if (tid < NUM_CLASSES) {
        int n = 0;
        for (int r = 0; r < TOPK; ++r) {
            if ((int)slab[r] == tid) {
                if (n < MAXPC) clist[tid * MAXPC + n] = (unsigned short)r;
                ++n;
            }
        }
        scount[tid] = (n < MAXPC) ? n : MAXPC;
    }
    __syncthreads();

    // per-class greedy NMS: one wave per class, shuffle broadcast, no barriers.
    // Cross-class IoU is ~1e-56 under CLASS_OFFSET=1e5 (never > 0.6), and the
    // offset cancels within-class, so per-class greedy on raw coords is exact.
    int wave = tid >> 6, lane = tid & 63;
    for (int c = wave; c < NUM_CLASSES; c += 16) {
        int n = scount[c];
        if (n <= 0) continue;
        int k0 = lane, k1 = lane + 64;
        int rk0 = -1, rk1 = -1, kp0 = 0, kp1 = 0;
        float x10=0,y10=0,x20=0,y20=0,a0=0, x11=0,y11=0,x21=0,y21=0,a1=0;
        if (k0 < n) {
            rk0 = clist[c * MAXPC + k0];
            x10 = bx1[rk0]; y10 = by1[rk0]; x20 = bx2[rk0]; y20 = by2[rk0];
            a0 = bar[rk0]; kp0 = skeep[rk0];
        }
        if (k1 < n) {
            rk1 = clist[c * MAXPC + k1];
            x11 = bx1[rk1]; y11 = by1[rk1]; x21 = bx2[rk1]; y21 = by2[rk1];
            a1 = bar[rk1]; kp1 = skeep[rk1];
        }
        for (int i = 0; i < n; ++i) {
            int src = i & 63;
            int ki; float xi1, yi1, xi2, yi2, ai;
            if (i < 64) {
                ki = __shfl(kp0, src);
                xi1 = __shfl(x10, src); yi1 = __shfl(y10, src);
                xi2 = __shfl(x20, src); yi2 = __shfl(y20, src);
                ai  = __shfl(a0, src);
            } else {
                ki = __shfl(kp1, src);
                xi1 = __shfl(x11, src); yi1 = __shfl(y11, src);
                xi2 = __shfl(x21, src); yi2 = __shfl(y21, src);
                ai  = __shfl(a1, src);
            }
            if (ki) {
                if (k0 > i && kp0) {
                    float xx1 = fmaxf(xi1, x10), yy1 = fmaxf(yi1, y10);
                    float xx2 = fminf(xi2, x20), yy2 = fminf(yi2, y20);
                    float w = fmaxf(1e-28f, xx2 - xx1), h = fmaxf(1e-28f, yy2 - yy1);
                    float inter = w * h;
                    if (inter / (ai + a0 - inter + 1e-14f) > NMS_THRESH) kp0 = 0;
                }
                if (k1 > i && kp1) {
                    float xx1 = fmaxf(xi1, x11), yy1 = fmaxf(yi1, y11);
                    float xx2 = fminf(xi2, x21), yy2 = fminf(yi2, y21);
                    float w = fmaxf(1e-28f, xx2 - xx1), h = fmaxf(1e-28f, yy2 - yy1);
                    float inter = w * h;
                    if (inter / (ai + a1 - inter + 1e-14f) > NMS_THRESH) kp1 = 0;
                }
            }
        }
        if (k0 < n) skeep[rk0] = kp0;
        if (k1 < n) skeep[rk1] = kp1;
    }
    __syncthreads();

    if (tid < TOPK) {
        float keepf = (float)skeep[tid];
        float img_w = (float)(*img_w_p), img_h = (float)(*img_h_p);
        float v0 = fminf(fmaxf(b0 / img_w, 0.0f), 1.0f);
        float v1 = fminf(fmaxf(b1 / img_h, 0.0f), 1.0f);
        float v2 = fminf(fmaxf(b2 / img_w, 0.0f), 1.0f);
        float v3 = fminf(fmaxf(b3 / img_h, 0.0f), 1.0f);
        out[tid * 4 + 0] = v0 * keepf;
        out[tid * 4 + 1] = v1 * keepf;
        out[tid * 4 + 2] = v2 * keepf;
        out[tid * 4 + 3] = v3 * keepf;
        out[4 * TOPK + tid] = prob * keepf;
        out[5 * TOPK + tid] = lblf;
        out[6 * TOPK + tid] = keepf;
    }
}

extern "C" void kernel_launch(void* const* d_in, const int* in_sizes, int n_in,
                              void* d_out, int out_size, void* d_ws, size_t ws_size,
                              hipStream_t stream) {
    const float* cls = (const float*)d_in[0];
    const float* regp = (const float*)d_in[1];
    const float* anchor_size = (const float*)d_in[2];
    const int* fmp_h = (const int*)d_in[3];
    const int* fmp_w = (const int*)d_in[4];
    const int* img_h = (const int*)d_in[5];
    const int* img_w = (const int*)d_in[6];
    int M = in_sizes[0];          // m * NUM_CLASSES
    int ka = in_sizes[2] / 2;

    unsigned int* hist = (unsigned int*)d_ws;       // NBINS
    unsigned int* counter = hist + NBINS;           // 1
    unsigned int* binB = counter + 1;               // 1
    unsigned int* cand = binB + 1;                  // CAP

    hipMemsetAsync(d_ws, 0, (size_t)(NBINS + 2) * sizeof(unsigned int), stream);

    hist_k<<<256, 256, 0, stream>>>(cls, M, hist);
    scan_k<<<1, 1024, 0, stream>>>(hist, binB);
    int blocks = (M + 255) / 256;
    if (blocks > 2048) blocks = 2048;
    compact_k<<<blocks, 256, 0, stream>>>(cls, M, binB, counter, cand);
    final_k<<<1, 1024, 0, stream>>>(cls, regp, anchor_size, fmp_h, fmp_w, img_h, img_w,
                                    ka, counter, cand, (float*)d_out);
}

// Round 3
// 106.960 us; speedup vs baseline: 10.1342x; 1.8204x over previous
//
#include <hip/hip_runtime.h>
#include <stdint.h>

#define NUM_CLASSES 80
#define TOPK 1000
#define NBINS 4096          // top 12 bits of flipped float key
#define CAP 4096            // candidate capacity
#define MAXPC 128           // max boxes per class in NMS lists
#define CONF_THRESH 0.05f
#define NMS_THRESH 0.6f
#define CTR_CLAMP 32.0f
#define SCALE_CLAMP 4.135166556742356f  // log(1000/16)
#define ANCH_STRIDE 32.0f

__device__ __forceinline__ unsigned int flip_key(unsigned int u) {
    return (u & 0x80000000u) ? ~u : (u | 0x80000000u);
}
__device__ __forceinline__ float unflip_key(unsigned int k) {
    unsigned int u = (k & 0x80000000u) ? (k ^ 0x80000000u) : ~k;
    return __uint_as_float(u);
}

// ---- histogram with LDS privatization ----
__global__ __launch_bounds__(256) void hist_k(const float* __restrict__ cls, int M,
                                              unsigned int* __restrict__ hist) {
    __shared__ unsigned int h[NBINS];
    for (int i = threadIdx.x; i < NBINS; i += 256) h[i] = 0u;
    __syncthreads();
    int tid = blockIdx.x * 256 + threadIdx.x;
    int stride = gridDim.x * 256;
    int M4 = M >> 2;
    const float4* cls4 = (const float4*)cls;
    for (int i = tid; i < M4; i += stride) {
        float4 v = cls4[i];
        atomicAdd(&h[flip_key(__float_as_uint(v.x)) >> 20], 1u);
        atomicAdd(&h[flip_key(__float_as_uint(v.y)) >> 20], 1u);
        atomicAdd(&h[flip_key(__float_as_uint(v.z)) >> 20], 1u);
        atomicAdd(&h[flip_key(__float_as_uint(v.w)) >> 20], 1u);
    }
    for (int i = (M4 << 2) + tid; i < M; i += stride)
        atomicAdd(&h[flip_key(__float_as_uint(cls[i])) >> 20], 1u);
    __syncthreads();
    for (int i = threadIdx.x; i < NBINS; i += 256) {
        unsigned int v = h[i];
        if (v) atomicAdd(&hist[i], v);
    }
}

// ---- single-wave suffix scan: find boundary bin ----
__global__ __launch_bounds__(64) void scan_k(const unsigned int* __restrict__ hist,
                                             unsigned int* __restrict__ binB) {
    int t = threadIdx.x;
    int base = t * 64;
    unsigned int local = 0;
    for (int i = 0; i < 64; ++i) local += hist[base + i];
    unsigned int suf = local;  // inclusive suffix over 64 chunk sums
    for (int off = 1; off < 64; off <<= 1) {
        unsigned int v = (unsigned int)__shfl_down((int)suf, off);
        if (t + off < 64) suf += v;
    }
    unsigned int above = suf - local;  // suffix of chunks strictly after t
    if (suf >= (unsigned)TOPK && above < (unsigned)TOPK) {
        unsigned int c = above;
        for (int b = base + 63; b >= base; --b) {
            c += hist[b];
            if (c >= (unsigned)TOPK) { *binB = (unsigned int)b; break; }
        }
    }
}

// ---- compaction: wave-aggregated append of composite u64 keys ----
__global__ __launch_bounds__(256) void compact_k(const float* __restrict__ cls, int M,
                          const unsigned int* __restrict__ binB,
                          unsigned int* __restrict__ counter,
                          uint64_t* __restrict__ cand) {
    unsigned int b = *binB;
    int lane = threadIdx.x & 63;
    int i = blockIdx.x * blockDim.x + threadIdx.x;
    int stride = gridDim.x * blockDim.x;
    for (; i < M; i += stride) {
        unsigned int key = flip_key(__float_as_uint(cls[i]));
        bool pred = ((key >> 20) >= b);
        unsigned long long m = __ballot(pred);
        if (m) {
            int leader = __ffsll((long long)m) - 1;
            unsigned int base = 0;
            if (lane == leader) base = atomicAdd(counter, (unsigned int)__popcll(m));
            base = (unsigned int)__shfl((int)base, leader);
            if (pred) {
                unsigned int p = base + (unsigned int)__popcll(m & ((1ull << lane) - 1ull));
                if (p < (unsigned)CAP)
                    cand[p] = ((uint64_t)key << 32) | (uint64_t)(0xFFFFFFFFu - (unsigned int)i);
            }
        }
    }
}

// ---- multi-CU rank selection: sorted[rank] = key (exact stable sort) ----
__global__ __launch_bounds__(256) void rank_k(const uint64_t* __restrict__ cand,
                                              const unsigned int* __restrict__ counter,
                                              uint64_t* __restrict__ sorted) {
    __shared__ uint64_t sk[CAP];
    unsigned int cnt0 = *counter;
    int N = (cnt0 < (unsigned)CAP) ? (int)cnt0 : CAP;
    for (int i = threadIdx.x; i < N; i += 256) sk[i] = cand[i];
    __syncthreads();
    int c = blockIdx.x * 64 + (threadIdx.x >> 2);   // candidate slot (4 threads each)
    int s = threadIdx.x & 3;
    if (c < N) {
        uint64_t my = sk[c];
        unsigned int cnt = 0;
        for (int j = s; j < N; j += 4) cnt += (sk[j] > my) ? 1u : 0u;
        cnt += (unsigned int)__shfl_xor((int)cnt, 1);
        cnt += (unsigned int)__shfl_xor((int)cnt, 2);
        if (s == 0 && cnt < (unsigned)TOPK) sorted[cnt] = my;
    }
}

// ---- final: decode + ballot class lists + per-class wave NMS + output ----
__global__ __launch_bounds__(1024) void final_k(
    const float* __restrict__ regp, const float* __restrict__ anchor_size,
    const int* __restrict__ fmp_w_p,
    const int* __restrict__ img_h_p, const int* __restrict__ img_w_p,
    int ka, const uint64_t* __restrict__ sorted, float* __restrict__ out)
{
    __shared__ float bx1[TOPK], by1[TOPK], bx2[TOPK], by2[TOPK], bar[TOPK];
    __shared__ int skeep[TOPK];
    __shared__ unsigned short clist[NUM_CLASSES * MAXPC];
    __shared__ int scount[NUM_CLASSES];
    __shared__ unsigned int chunkCnt[16][NUM_CLASSES];
    __shared__ unsigned int chunkBase[16][NUM_CLASSES];

    int tid = threadIdx.x;
    int fmp_w = *fmp_w_p;

    float prob = 0.0f, lblf = 0.0f;
    float b0 = 0.f, b1 = 0.f, b2 = 0.f, b3 = 0.f;
    int lab = 255;
    if (tid < TOPK) {
        uint64_t k = sorted[tid];
        unsigned int idx = 0xFFFFFFFFu - (unsigned int)(k & 0xFFFFFFFFull);
        float logit = unflip_key((unsigned int)(k >> 32));
        prob = 1.0f / (1.0f + expf(-logit));
        lab = (int)(idx % NUM_CLASSES);
        int aidx = (int)(idx / NUM_CLASSES);
        int g = aidx / ka, kk = aidx % ka;
        int xg = g % fmp_w, yg = g / fmp_w;
        float ax = (xg + 0.5f) * ANCH_STRIDE, ay = (yg + 0.5f) * ANCH_STRIDE;
        float aw = anchor_size[kk * 2 + 0], ah = anchor_size[kk * 2 + 1];
        float r0 = regp[aidx * 4 + 0], r1 = regp[aidx * 4 + 1];
        float r2 = regp[aidx * 4 + 2], r3 = regp[aidx * 4 + 3];
        float ox = fminf(fmaxf(r0 * aw, -CTR_CLAMP), CTR_CLAMP);
        float oy = fminf(fmaxf(r1 * ah, -CTR_CLAMP), CTR_CLAMP);
        float cx = ax + ox, cy = ay + oy;
        float w = aw * expf(fminf(r2, SCALE_CLAMP));
        float h = ah * expf(fminf(r3, SCALE_CLAMP));
        b0 = cx - 0.5f * w; b1 = cy - 0.5f * h;
        b2 = cx + 0.5f * w; b3 = cy + 0.5f * h;
        lblf = (float)lab;
        bx1[tid] = b0; by1[tid] = b1; bx2[tid] = b2; by2[tid] = b3;
        bar[tid] = (b2 - b0) * (b3 - b1);   // class offset cancels within-class
        skeep[tid] = (prob > CONF_THRESH) ? 1 : 0;
    }

    // ballot-based stable per-class lists: chunk = wave (64 ranks), pos via popc
    int wv = tid >> 6, lane = tid & 63;
    unsigned long long ltmask = (lane == 0) ? 0ull : ((~0ull) >> (64 - lane));
    unsigned int mypos = 0;
    for (int c = 0; c < NUM_CLASSES; ++c) {
        unsigned long long m = __ballot(lab == c);
        if (lab == c) mypos = (unsigned int)__popcll(m & ltmask);
        if (lane == 0) chunkCnt[wv][c] = (unsigned int)__popcll(m);
    }
    __syncthreads();
    if (tid < NUM_CLASSES) {
        unsigned int run = 0;
        for (int w = 0; w < 16; ++w) { chunkBase[w][tid] = run; run += chunkCnt[w][tid]; }
        scount[tid] = (run < (unsigned)MAXPC) ? (int)run : MAXPC;
    }
    __syncthreads();
    if (tid < TOPK) {
        unsigned int p = chunkBase[wv][lab] + mypos;
        if (p < (unsigned)MAXPC) clist[lab * MAXPC + p] = (unsigned short)tid;
    }
    __syncthreads();

    // per-class greedy NMS: one wave per class, shuffle broadcast, no barriers.
    // Cross-class IoU under CLASS_OFFSET=1e5 is ~1e-56 (never > 0.6); offset
    // cancels within-class, so per-class greedy on raw coords is exact.
    for (int c = wv; c < NUM_CLASSES; c += 16) {
        int n = scount[c];
        if (n <= 0) continue;
        int k0 = lane, k1 = lane + 64;
        int rk0 = -1, rk1 = -1, kp0 = 0, kp1 = 0;
        float x10=0,y10=0,x20=0,y20=0,a0=0, x11=0,y11=0,x21=0,y21=0,a1=0;
        if (k0 < n) {
            rk0 = clist[c * MAXPC + k0];
            x10 = bx1[rk0]; y10 = by1[rk0]; x20 = bx2[rk0]; y20 = by2[rk0];
            a0 = bar[rk0]; kp0 = skeep[rk0];
        }
        if (k1 < n) {
            rk1 = clist[c * MAXPC + k1];
            x11 = bx1[rk1]; y11 = by1[rk1]; x21 = bx2[rk1]; y21 = by2[rk1];
            a1 = bar[rk1]; kp1 = skeep[rk1];
        }
        for (int i = 0; i < n; ++i) {
            int src = i & 63;
            int ki; float xi1, yi1, xi2, yi2, ai;
            if (i < 64) {
                ki = __shfl(kp0, src);
                xi1 = __shfl(x10, src); yi1 = __shfl(y10, src);
                xi2 = __shfl(x20, src); yi2 = __shfl(y20, src);
                ai  = __shfl(a0, src);
            } else {
                ki = __shfl(kp1, src);
                xi1 = __shfl(x11, src); yi1 = __shfl(y11, src);
                xi2 = __shfl(x21, src); yi2 = __shfl(y21, src);
                ai  = __shfl(a1, src);
            }
            if (ki) {
                if (k0 > i && kp0) {
                    float xx1 = fmaxf(xi1, x10), yy1 = fmaxf(yi1, y10);
                    float xx2 = fminf(xi2, x20), yy2 = fminf(yi2, y20);
                    float w = fmaxf(1e-28f, xx2 - xx1), h = fmaxf(1e-28f, yy2 - yy1);
                    float inter = w * h;
                    if (inter / (ai + a0 - inter + 1e-14f) > NMS_THRESH) kp0 = 0;
                }
                if (k1 > i && kp1) {
                    float xx1 = fmaxf(xi1, x11), yy1 = fmaxf(yi1, y11);
                    float xx2 = fminf(xi2, x21), yy2 = fminf(yi2, y21);
                    float w = fmaxf(1e-28f, xx2 - xx1), h = fmaxf(1e-28f, yy2 - yy1);
                    float inter = w * h;
                    if (inter / (ai + a1 - inter + 1e-14f) > NMS_THRESH) kp1 = 0;
                }
            }
        }
        if (k0 < n) skeep[rk0] = kp0;
        if (k1 < n) skeep[rk1] = kp1;
    }
    __syncthreads();

    if (tid < TOPK) {
        float keepf = (float)skeep[tid];
        float img_w = (float)(*img_w_p), img_h = (float)(*img_h_p);
        float v0 = fminf(fmaxf(b0 / img_w, 0.0f), 1.0f);
        float v1 = fminf(fmaxf(b1 / img_h, 0.0f), 1.0f);
        float v2 = fminf(fmaxf(b2 / img_w, 0.0f), 1.0f);
        float v3 = fminf(fmaxf(b3 / img_h, 0.0f), 1.0f);
        out[tid * 4 + 0] = v0 * keepf;
        out[tid * 4 + 1] = v1 * keepf;
        out[tid * 4 + 2] = v2 * keepf;
        out[tid * 4 + 3] = v3 * keepf;
        out[4 * TOPK + tid] = prob * keepf;
        out[5 * TOPK + tid] = lblf;
        out[6 * TOPK + tid] = keepf;
    }
}

extern "C" void kernel_launch(void* const* d_in, const int* in_sizes, int n_in,
                              void* d_out, int out_size, void* d_ws, size_t ws_size,
                              hipStream_t stream) {
    const float* cls = (const float*)d_in[0];
    const float* regp = (const float*)d_in[1];
    const float* anchor_size = (const float*)d_in[2];
    const int* fmp_w = (const int*)d_in[4];
    const int* img_h = (const int*)d_in[5];
    const int* img_w = (const int*)d_in[6];
    int M = in_sizes[0];          // m * NUM_CLASSES
    int ka = in_sizes[2] / 2;

    uint8_t* ws = (uint8_t*)d_ws;
    unsigned int* hist = (unsigned int*)ws;                 // [4096] @0
    unsigned int* counter = (unsigned int*)(ws + 16384);    // @16384
    unsigned int* binB = (unsigned int*)(ws + 16388);       // @16388
    uint64_t* cand = (uint64_t*)(ws + 16400);               // [CAP] @16400
    uint64_t* sorted = (uint64_t*)(ws + 16400 + CAP * 8);   // [1024]

    hipMemsetAsync(d_ws, 0, 16392, stream);

    hist_k<<<256, 256, 0, stream>>>(cls, M, hist);
    scan_k<<<1, 64, 0, stream>>>(hist, binB);
    int blocks = (M + 255) / 256;
    if (blocks > 512) blocks = 512;
    compact_k<<<blocks, 256, 0, stream>>>(cls, M, binB, counter, cand);
    rank_k<<<CAP / 64, 256, 0, stream>>>(cand, counter, sorted);
    final_k<<<1, 1024, 0, stream>>>(regp, anchor_size, fmp_w, img_h, img_w,
                                    ka, sorted, (float*)d_out);
}

// Round 4
// 92.213 us; speedup vs baseline: 11.7550x; 1.1599x over previous
//
#include <hip/hip_runtime.h>
#include <stdint.h>

#define NUM_CLASSES 80
#define TOPK 1000
#define NBINS 4096          // top 12 bits of flipped float key
#define CAP 4096            // candidate capacity
#define MAXPC 128           // max boxes per class in NMS lists
#define CONF_THRESH 0.05f
#define NMS_THRESH 0.6f
#define CTR_CLAMP 32.0f
#define SCALE_CLAMP 4.135166556742356f  // log(1000/16)
#define ANCH_STRIDE 32.0f
#define HIST_BLOCKS 256

__device__ __forceinline__ unsigned int flip_key(unsigned int u) {
    return (u & 0x80000000u) ? ~u : (u | 0x80000000u);
}
__device__ __forceinline__ float unflip_key(unsigned int k) {
    unsigned int u = (k & 0x80000000u) ? (k ^ 0x80000000u) : ~k;
    return __uint_as_float(u);
}

// ---- tiny workspace zero (replaces the 39us graph-memset blit node) ----
__global__ __launch_bounds__(256) void zero_k(unsigned int* __restrict__ w, int nwords) {
    int i = blockIdx.x * 256 + threadIdx.x;
    if (i < nwords) w[i] = 0u;
}

// ---- histogram (LDS-privatized) + fused boundary scan in the last block ----
__global__ __launch_bounds__(256) void hist_k(const float* __restrict__ cls, int M,
                                              unsigned int* __restrict__ hist,
                                              unsigned int* __restrict__ ticket,
                                              unsigned int* __restrict__ binB) {
    __shared__ unsigned int h[NBINS];
    __shared__ unsigned int suf[256];
    __shared__ int lastFlag;
    for (int i = threadIdx.x; i < NBINS; i += 256) h[i] = 0u;
    __syncthreads();

    int tid = blockIdx.x * 256 + threadIdx.x;
    int stride = gridDim.x * 256;
    const float4* cls4 = (const float4*)cls;
    int M4 = M >> 2;
    for (int i = tid; i < M4; i += stride) {
        float4 v = cls4[i];
        atomicAdd(&h[flip_key(__float_as_uint(v.x)) >> 20], 1u);
        atomicAdd(&h[flip_key(__float_as_uint(v.y)) >> 20], 1u);
        atomicAdd(&h[flip_key(__float_as_uint(v.z)) >> 20], 1u);
        atomicAdd(&h[flip_key(__float_as_uint(v.w)) >> 20], 1u);
    }
    for (int i = (M4 << 2) + tid; i < M; i += stride)
        atomicAdd(&h[flip_key(__float_as_uint(cls[i])) >> 20], 1u);
    __syncthreads();
    for (int i = threadIdx.x; i < NBINS; i += 256) {
        unsigned int v = h[i];
        if (v) atomicAdd(&hist[i], v);
    }
    __syncthreads();                    // all merge atomics issued+drained (vmcnt(0) before barrier)
    if (threadIdx.x == 0) {
        __threadfence();                // order hist atomics before ticket
        lastFlag = (atomicAdd(ticket, 1u) == (unsigned)gridDim.x - 1u) ? 1 : 0;
    }
    __syncthreads();
    if (!lastFlag) return;

    // last block: coherent re-read of merged hist, suffix-scan, locate boundary
    for (int i = threadIdx.x; i < NBINS; i += 256)
        h[i] = atomicAdd(&hist[i], 0u);  // atomic read: device-coherent point
    __syncthreads();
    int t = threadIdx.x;
    unsigned int s = 0;
    #pragma unroll
    for (int b = 0; b < 16; ++b) s += h[16 * t + b];
    suf[t] = s;
    __syncthreads();
    for (int off = 1; off < 256; off <<= 1) {
        unsigned int v = (t + off < 256) ? suf[t + off] : 0u;
        __syncthreads();
        suf[t] += v;
        __syncthreads();
    }
    unsigned int mine = suf[t];
    unsigned int nxt = (t < 255) ? suf[t + 1] : 0u;
    if (mine >= (unsigned)TOPK && nxt < (unsigned)TOPK) {
        unsigned int c = nxt;
        for (int b = 16 * t + 15; b >= 16 * t; --b) {
            c += h[b];
            if (c >= (unsigned)TOPK) { *binB = (unsigned int)b; break; }
        }
    }
}

// ---- compaction: float4 + wave-aggregated append of composite u64 keys ----
__global__ __launch_bounds__(256) void compact_k(const float* __restrict__ cls, int M,
                          const unsigned int* __restrict__ binB,
                          unsigned int* __restrict__ counter,
                          uint64_t* __restrict__ cand) {
    unsigned int b = *binB;
    int lane = threadIdx.x & 63;
    int tid = blockIdx.x * 256 + threadIdx.x;
    int stride = gridDim.x * 256;
    const float4* cls4 = (const float4*)cls;
    int M4 = M >> 2;
    for (int i = tid; i < M4; i += stride) {
        float4 v = cls4[i];
        unsigned int k[4];
        k[0] = flip_key(__float_as_uint(v.x));
        k[1] = flip_key(__float_as_uint(v.y));
        k[2] = flip_key(__float_as_uint(v.z));
        k[3] = flip_key(__float_as_uint(v.w));
        #pragma unroll
        for (int j = 0; j < 4; ++j) {
            bool pred = ((k[j] >> 20) >= b);
            unsigned long long m = __ballot(pred);
            if (m) {
                int leader = __ffsll((long long)m) - 1;
                unsigned int base = 0;
                if (lane == leader) base = atomicAdd(counter, (unsigned int)__popcll(m));
                base = (unsigned int)__shfl((int)base, leader);
                if (pred) {
                    unsigned int p = base + (unsigned int)__popcll(m & ((1ull << lane) - 1ull));
                    unsigned int gi = (unsigned int)(i * 4 + j);
                    if (p < (unsigned)CAP)
                        cand[p] = ((uint64_t)k[j] << 32) | (uint64_t)(0xFFFFFFFFu - gi);
                }
            }
        }
    }
    for (int i = (M4 << 2) + tid; i < M; i += stride) {
        unsigned int key = flip_key(__float_as_uint(cls[i]));
        if ((key >> 20) >= b) {
            unsigned int p = atomicAdd(counter, 1u);
            if (p < (unsigned)CAP)
                cand[p] = ((uint64_t)key << 32) | (uint64_t)(0xFFFFFFFFu - (unsigned int)i);
        }
    }
}

// ---- multi-CU rank selection: sorted[rank] = key (exact stable sort) ----
__global__ __launch_bounds__(256) void rank_k(const uint64_t* __restrict__ cand,
                                              const unsigned int* __restrict__ counter,
                                              uint64_t* __restrict__ sorted) {
    __shared__ uint64_t sk[CAP];
    unsigned int cnt0 = *counter;
    int N = (cnt0 < (unsigned)CAP) ? (int)cnt0 : CAP;
    for (int i = threadIdx.x; i < N; i += 256) sk[i] = cand[i];
    __syncthreads();
    int c = blockIdx.x * 32 + (threadIdx.x >> 3);   // candidate slot (8 threads each)
    int s = threadIdx.x & 7;
    if (c < N) {
        uint64_t my = sk[c];
        unsigned int cnt = 0;
        for (int j = s; j < N; j += 8) cnt += (sk[j] > my) ? 1u : 0u;
        cnt += (unsigned int)__shfl_xor((int)cnt, 1);
        cnt += (unsigned int)__shfl_xor((int)cnt, 2);
        cnt += (unsigned int)__shfl_xor((int)cnt, 4);
        if (s == 0 && cnt < (unsigned)TOPK) sorted[cnt] = my;
    }
}

// ---- final: decode + ballot class lists + per-class wave NMS + output ----
__global__ __launch_bounds__(1024) void final_k(
    const float* __restrict__ regp, const float* __restrict__ anchor_size,
    const int* __restrict__ fmp_w_p,
    const int* __restrict__ img_h_p, const int* __restrict__ img_w_p,
    int ka, const uint64_t* __restrict__ sorted, float* __restrict__ out)
{
    __shared__ float bx1[TOPK], by1[TOPK], bx2[TOPK], by2[TOPK], bar[TOPK];
    __shared__ int skeep[TOPK];
    __shared__ unsigned short clist[NUM_CLASSES * MAXPC];
    __shared__ int scount[NUM_CLASSES];
    __shared__ unsigned int chunkCnt[16][NUM_CLASSES];
    __shared__ unsigned int chunkBase[16][NUM_CLASSES];

    int tid = threadIdx.x;
    int fmp_w = *fmp_w_p;

    float prob = 0.0f, lblf = 0.0f;
    float b0 = 0.f, b1 = 0.f, b2 = 0.f, b3 = 0.f;
    int lab = 255;
    if (tid < TOPK) {
        uint64_t k = sorted[tid];
        unsigned int idx = 0xFFFFFFFFu - (unsigned int)(k & 0xFFFFFFFFull);
        float logit = unflip_key((unsigned int)(k >> 32));
        prob = 1.0f / (1.0f + expf(-logit));
        lab = (int)(idx % NUM_CLASSES);
        int aidx = (int)(idx / NUM_CLASSES);
        int g = aidx / ka, kk = aidx % ka;
        int xg = g % fmp_w, yg = g / fmp_w;
        float ax = (xg + 0.5f) * ANCH_STRIDE, ay = (yg + 0.5f) * ANCH_STRIDE;
        float aw = anchor_size[kk * 2 + 0], ah = anchor_size[kk * 2 + 1];
        float r0 = regp[aidx * 4 + 0], r1 = regp[aidx * 4 + 1];
        float r2 = regp[aidx * 4 + 2], r3 = regp[aidx * 4 + 3];
        float ox = fminf(fmaxf(r0 * aw, -CTR_CLAMP), CTR_CLAMP);
        float oy = fminf(fmaxf(r1 * ah, -CTR_CLAMP), CTR_CLAMP);
        float cx = ax + ox, cy = ay + oy;
        float w = aw * expf(fminf(r2, SCALE_CLAMP));
        float h = ah * expf(fminf(r3, SCALE_CLAMP));
        b0 = cx - 0.5f * w; b1 = cy - 0.5f * h;
        b2 = cx + 0.5f * w; b3 = cy + 0.5f * h;
        lblf = (float)lab;
        bx1[tid] = b0; by1[tid] = b1; bx2[tid] = b2; by2[tid] = b3;
        bar[tid] = (b2 - b0) * (b3 - b1);   // class offset cancels within-class
        skeep[tid] = (prob > CONF_THRESH) ? 1 : 0;
    }

    // ballot-based stable per-class lists
    int wv = tid >> 6, lane = tid & 63;
    unsigned long long ltmask = (lane == 0) ? 0ull : ((~0ull) >> (64 - lane));
    unsigned int mypos = 0;
    for (int c = 0; c < NUM_CLASSES; ++c) {
        unsigned long long m = __ballot(lab == c);
        if (lab == c) mypos = (unsigned int)__popcll(m & ltmask);
        if (lane == 0) chunkCnt[wv][c] = (unsigned int)__popcll(m);
    }
    __syncthreads();
    if (tid < NUM_CLASSES) {
        unsigned int run = 0;
        for (int w = 0; w < 16; ++w) { chunkBase[w][tid] = run; run += chunkCnt[w][tid]; }
        scount[tid] = (run < (unsigned)MAXPC) ? (int)run : MAXPC;
    }
    __syncthreads();
    if (tid < TOPK) {
        unsigned int p = chunkBase[wv][lab] + mypos;
        if (p < (unsigned)MAXPC) clist[lab * MAXPC + p] = (unsigned short)tid;
    }
    __syncthreads();

    // per-class greedy NMS: one wave per class, shuffle broadcast, no barriers.
    // Cross-class IoU under CLASS_OFFSET=1e5 is ~1e-56 (never > 0.6); offset
    // cancels within-class, so per-class greedy on raw coords is exact.
    for (int c = wv; c < NUM_CLASSES; c += 16) {
        int n = scount[c];
        if (n <= 0) continue;
        int k0 = lane, k1 = lane + 64;
        int rk0 = -1, rk1 = -1, kp0 = 0, kp1 = 0;
        float x10=0,y10=0,x20=0,y20=0,a0=0, x11=0,y11=0,x21=0,y21=0,a1=0;
        if (k0 < n) {
            rk0 = clist[c * MAXPC + k0];
            x10 = bx1[rk0]; y10 = by1[rk0]; x20 = bx2[rk0]; y20 = by2[rk0];
            a0 = bar[rk0]; kp0 = skeep[rk0];
        }
        if (k1 < n) {
            rk1 = clist[c * MAXPC + k1];
            x11 = bx1[rk1]; y11 = by1[rk1]; x21 = bx2[rk1]; y21 = by2[rk1];
            a1 = bar[rk1]; kp1 = skeep[rk1];
        }
        for (int i = 0; i < n; ++i) {
            int src = i & 63;
            int ki; float xi1, yi1, xi2, yi2, ai;
            if (i < 64) {
                ki = __shfl(kp0, src);
                xi1 = __shfl(x10, src); yi1 = __shfl(y10, src);
                xi2 = __shfl(x20, src); yi2 = __shfl(y20, src);
                ai  = __shfl(a0, src);
            } else {
                ki = __shfl(kp1, src);
                xi1 = __shfl(x11, src); yi1 = __shfl(y11, src);
                xi2 = __shfl(x21, src); yi2 = __shfl(y21, src);
                ai  = __shfl(a1, src);
            }
            if (ki) {
                if (k0 > i && kp0) {
                    float xx1 = fmaxf(xi1, x10), yy1 = fmaxf(yi1, y10);
                    float xx2 = fminf(xi2, x20), yy2 = fminf(yi2, y20);
                    float w = fmaxf(1e-28f, xx2 - xx1), h = fmaxf(1e-28f, yy2 - yy1);
                    float inter = w * h;
                    if (inter / (ai + a0 - inter + 1e-14f) > NMS_THRESH) kp0 = 0;
                }
                if (k1 > i && kp1) {
                    float xx1 = fmaxf(xi1, x11), yy1 = fmaxf(yi1, y11);
                    float xx2 = fminf(xi2, x21), yy2 = fminf(yi2, y21);
                    float w = fmaxf(1e-28f, xx2 - xx1), h = fmaxf(1e-28f, yy2 - yy1);
                    float inter = w * h;
                    if (inter / (ai + a1 - inter + 1e-14f) > NMS_THRESH) kp1 = 0;
                }
            }
        }
        if (k0 < n) skeep[rk0] = kp0;
        if (k1 < n) skeep[rk1] = kp1;
    }
    __syncthreads();

    if (tid < TOPK) {
        float keepf = (float)skeep[tid];
        float img_w = (float)(*img_w_p), img_h = (float)(*img_h_p);
        float v0 = fminf(fmaxf(b0 / img_w, 0.0f), 1.0f);
        float v1 = fminf(fmaxf(b1 / img_h, 0.0f), 1.0f);
        float v2 = fminf(fmaxf(b2 / img_w, 0.0f), 1.0f);
        float v3 = fminf(fmaxf(b3 / img_h, 0.0f), 1.0f);
        out[tid * 4 + 0] = v0 * keepf;
        out[tid * 4 + 1] = v1 * keepf;
        out[tid * 4 + 2] = v2 * keepf;
        out[tid * 4 + 3] = v3 * keepf;
        out[4 * TOPK + tid] = prob * keepf;
        out[5 * TOPK + tid] = lblf;
        out[6 * TOPK + tid] = keepf;
    }
}

extern "C" void kernel_launch(void* const* d_in, const int* in_sizes, int n_in,
                              void* d_out, int out_size, void* d_ws, size_t ws_size,
                              hipStream_t stream) {
    const float* cls = (const float*)d_in[0];
    const float* regp = (const float*)d_in[1];
    const float* anchor_size = (const float*)d_in[2];
    const int* fmp_w = (const int*)d_in[4];
    const int* img_h = (const int*)d_in[5];
    const int* img_w = (const int*)d_in[6];
    int M = in_sizes[0];          // m * NUM_CLASSES
    int ka = in_sizes[2] / 2;

    uint8_t* ws = (uint8_t*)d_ws;
    unsigned int* hist = (unsigned int*)ws;                 // [4096]  @0
    unsigned int* counter = (unsigned int*)(ws + 16384);    // @16384
    unsigned int* ticket = (unsigned int*)(ws + 16388);     // @16388
    unsigned int* binB = (unsigned int*)(ws + 16392);       // @16392
    uint64_t* cand = (uint64_t*)(ws + 16400);               // [CAP]   @16400
    uint64_t* sorted = (uint64_t*)(ws + 16400 + CAP * 8);   // [1024]

    int zwords = NBINS + 3;  // hist + counter + ticket + binB
    zero_k<<<(zwords + 255) / 256, 256, 0, stream>>>((unsigned int*)ws, zwords);

    hist_k<<<HIST_BLOCKS, 256, 0, stream>>>(cls, M, hist, ticket, binB);

    int M4 = M >> 2;
    int cblocks = (M4 + 255) / 256;
    if (cblocks > 690) cblocks = 690;
    compact_k<<<cblocks, 256, 0, stream>>>(cls, M, binB, counter, cand);

    rank_k<<<CAP / 32, 256, 0, stream>>>(cand, counter, sorted);
    final_k<<<1, 1024, 0, stream>>>(regp, anchor_size, fmp_w, img_h, img_w,
                                    ka, sorted, (float*)d_out);
}